// Round 4
// baseline (178.478 us; speedup 1.0000x reference)
//
#include <hip/hip_runtime.h>
#include <hip/hip_bf16.h>

typedef __attribute__((ext_vector_type(8))) short bf16x8;
typedef __attribute__((ext_vector_type(4))) float f32x4;

#define NB 32
#define NS 512
#define ND 1024

__device__ __forceinline__ unsigned short f2bf(float f) {
  unsigned int u = __float_as_uint(f);
  u = (u + 0x7FFFu + ((u >> 16) & 1u)) >> 16;  // RNE: truncation bias would be ~2.5e-3
  return (unsigned short)u;
}

// ---------- normalized aspect -> bf16 ----------
__global__ void anorm_kernel(const float* __restrict__ aspect,
                             unsigned short* __restrict__ a_n) {
  int b = blockIdx.x;
  int t = threadIdx.x;
  const float4* p = (const float4*)(aspect + (size_t)b * ND);
  float4 v = p[t];
  float s = v.x * v.x + v.y * v.y + v.z * v.z + v.w * v.w;
#pragma unroll
  for (int off = 32; off >= 1; off >>= 1) s += __shfl_down(s, off);
  __shared__ float red[4];
  if ((t & 63) == 0) red[t >> 6] = s;
  __syncthreads();
  float tot = red[0] + red[1] + red[2] + red[3];
  float inv = (tot > 0.f) ? (1.f / sqrtf(tot)) : 0.f;
  ushort4 u;
  u.x = f2bf(v.x * inv); u.y = f2bf(v.y * inv);
  u.z = f2bf(v.z * inv); u.w = f2bf(v.w * inv);
  ((ushort4*)(a_n + (size_t)b * ND))[t] = u;
}

// ---------- precompute normalized embeddings as bf16 (one wave/row) ----------
__global__ __launch_bounds__(256)
void enormbf_kernel(const float* __restrict__ emb,
                    unsigned short* __restrict__ eN) {
  int wave = threadIdx.x >> 6, lane = threadIdx.x & 63;
  size_t row = (size_t)blockIdx.x * 4 + wave;  // 0..16383
  const float4* p = (const float4*)(emb + row * ND);
  float4 v[4];
  float s = 0.f;
#pragma unroll
  for (int j = 0; j < 4; ++j) {
    v[j] = p[lane + 64 * j];
    s += v[j].x * v[j].x + v[j].y * v[j].y + v[j].z * v[j].z + v[j].w * v[j].w;
  }
#pragma unroll
  for (int off = 32; off >= 1; off >>= 1) s += __shfl_xor(s, off);
  float inv = (s > 0.f) ? (1.f / sqrtf(s)) : 0.f;
  ushort4* o = (ushort4*)(eN + row * ND);
#pragma unroll
  for (int j = 0; j < 4; ++j) {
    ushort4 u;
    u.x = f2bf(v[j].x * inv); u.y = f2bf(v[j].y * inv);
    u.z = f2bf(v[j].z * inv); u.w = f2bf(v[j].w * inv);
    o[lane + 64 * j] = u;
  }
}

// ---------- GEMM v4: barrier-free K-loop.
// A-frags: global->VGPR dwordx4, double-buffered one iter ahead (L2-served,
// XCD-aware grid keeps the 8 nt-siblings on one XCD).
// B-frags: read-only circulant windows in LDS; only 6 distinct windows/iter
// (circulant overlap: (r,kk=0) window == (r-2,kk=1) window).
// No __syncthreads after the initial stage -> no barrier drain. ----------
__global__ __launch_bounds__(256, 3)
void corr_gemm4_kernel(const unsigned short* __restrict__ eN,
                       const unsigned short* __restrict__ a_n,
                       float* __restrict__ out) {
  // copies[p][x] = a[(x + (896 - n0) + p) & 1023]; block needs idx in [0,1151]
  __shared__ unsigned short copies[8][1160];

  const int b = blockIdx.x, mt = blockIdx.y, nt = blockIdx.z;
  const int n0 = nt * 128, m0 = mt * 128;
  const int t = threadIdx.x;

  // stage windowed shift-copies (once per block): 8 x 1152 entries
  {
    const unsigned short* an = a_n + (size_t)b * ND;
    int p = t & 7;
    int x0 = (t >> 3) * 36;  // 32 threads/copy x 36 = 1152
    int base = (896 - n0 + p) & 1023;
#pragma unroll
    for (int j = 0; j < 36; j += 4) {
      ushort4 u;
      u.x = an[(base + x0 + j + 0) & 1023];
      u.y = an[(base + x0 + j + 1) & 1023];
      u.z = an[(base + x0 + j + 2) & 1023];
      u.w = an[(base + x0 + j + 3) & 1023];
      *(ushort4*)&copies[p][x0 + j] = u;
    }
  }
  __syncthreads();  // the ONLY barrier

  const int lane = t & 63, wv = t >> 6;
  const int wm = wv >> 1, wn = wv & 1;  // 2x2 waves over 128x128
  const int q = lane >> 4, l16 = lane & 15;

  // per-lane A row pointers: frag(r,kk,it) = arow[r] + it*64 + kk*32 (elems)
  const unsigned short* arow[4];
#pragma unroll
  for (int r = 0; r < 4; ++r)
    arow[r] = eN + ((size_t)b * NS + m0 + wm * 64 + r * 16 + l16) * ND + q * 8;

  // B window geometry: idx(r,kk,j) = u + k0 + kk*32 - r*16 + j, u = 8q+128-wn*64-l16
  // p = u&7 is lane-constant (all window starts are 0 mod 8 apart).
  // bwin[j] at element offset k0 + 16*j from bbase; (r,kk) -> j = 3 - r + 2*kk.
  const int u = 8 * q + 128 - wn * 64 - l16;  // >= 49
  const int p = u & 7;
  const unsigned short* bbase = &copies[p][(u - p) - 48];  // u-p >= 48, so >= copies[p][0]

  f32x4 acc[4][4];
#pragma unroll
  for (int i = 0; i < 4; ++i)
#pragma unroll
    for (int j = 0; j < 4; ++j)
      acc[i][j] = (f32x4){0.f, 0.f, 0.f, 0.f};

  bf16x8 Abuf[2][8];  // [phase][kk*4+r]
#pragma unroll
  for (int h = 0; h < 8; ++h)
    Abuf[0][h] = *(const bf16x8*)(arow[h & 3] + (h >> 2) * 32);

#pragma unroll
  for (int it = 0; it < 16; ++it) {
    const int cur = it & 1, nxt = cur ^ 1;
    if (it + 1 < 16) {
      const int k0n = (it + 1) * 64;
#pragma unroll
      for (int h = 0; h < 8; ++h)
        Abuf[nxt][h] = *(const bf16x8*)(arow[h & 3] + k0n + (h >> 2) * 32);
    }
    const int k0 = it * 64;
    bf16x8 bwin[6];
#pragma unroll
    for (int j = 0; j < 6; ++j)
      bwin[j] = *(const bf16x8*)(bbase + k0 + 16 * j);

#pragma unroll
    for (int kk = 0; kk < 2; ++kk) {
#pragma unroll
      for (int i = 0; i < 4; ++i) {
        bf16x8 af = Abuf[cur][kk * 4 + i];
#pragma unroll
        for (int j2 = 0; j2 < 4; ++j2)
          acc[i][j2] = __builtin_amdgcn_mfma_f32_16x16x32_bf16(
              af, bwin[3 - j2 + 2 * kk], acc[i][j2], 0, 0, 0);
      }
    }
  }

  // epilogue: C/D layout col=lane&15, row=(lane>>4)*4+reg
  float* outB = out + ((size_t)b * NS + m0) * ND + n0;
#pragma unroll
  for (int i = 0; i < 4; ++i) {
#pragma unroll
    for (int rg = 0; rg < 4; ++rg) {
      int s = wm * 64 + i * 16 + q * 4 + rg;
      float* orow = outB + (size_t)s * ND + wn * 64 + l16;
#pragma unroll
      for (int j = 0; j < 4; ++j)
        orow[j * 16] = acc[i][j][rg];
    }
  }
}

// ---------- fallback path (round-1 kernels) in case ws is small ----------
__global__ void enorm_kernel(const float* __restrict__ emb,
                             float* __restrict__ inv_norm) {
  int wave = threadIdx.x >> 6;
  int lane = threadIdx.x & 63;
  int row = blockIdx.x * 4 + wave;
  const float4* p = (const float4*)(emb + (size_t)row * ND);
  float s = 0.f;
#pragma unroll
  for (int j = 0; j < 4; ++j) {
    float4 v = p[lane + 64 * j];
    s += v.x * v.x + v.y * v.y + v.z * v.z + v.w * v.w;
  }
#pragma unroll
  for (int off = 32; off >= 1; off >>= 1) s += __shfl_down(s, off);
  if (lane == 0) inv_norm[row] = (s > 0.f) ? (1.f / sqrtf(s)) : 0.f;
}

__global__ __launch_bounds__(256)
void corr_gemm_kernel(const float* __restrict__ emb,
                      const float* __restrict__ inv_norm,
                      const unsigned short* __restrict__ a_n,
                      float* __restrict__ out) {
  __shared__ unsigned short copies[8][2056];
  __shared__ unsigned short Atile[128][40];

  const int nt = blockIdx.x, mt = blockIdx.y, b = blockIdx.z;
  const int n0 = nt * 128, m0 = mt * 128;
  const int t = threadIdx.x;

  {
    const unsigned short* an = a_n + (size_t)b * ND;
    int p = t & 7;
    int x0 = (t >> 3) * 64;
#pragma unroll
    for (int j = 0; j < 64; j += 4) {
      ushort4 u;
      u.x = an[(x0 + j + 0 + p) & 1023];
      u.y = an[(x0 + j + 1 + p) & 1023];
      u.z = an[(x0 + j + 2 + p) & 1023];
      u.w = an[(x0 + j + 3 + p) & 1023];
      *(ushort4*)&copies[p][x0 + j] = u;
    }
  }

  const int ar = t >> 3;
  const int ac = (t & 7) * 4;
  float invn[4];
#pragma unroll
  for (int w = 0; w < 4; ++w)
    invn[w] = inv_norm[b * NS + m0 + ar + 32 * w];

  const int lane = t & 63;
  const int wv = t >> 6;
  const int wm = wv >> 1, wn = wv & 1;
  const int q = lane >> 4, l16 = lane & 15;

  f32x4 acc[4][4];
#pragma unroll
  for (int i = 0; i < 4; ++i)
#pragma unroll
    for (int j = 0; j < 4; ++j)
      acc[i][j] = (f32x4){0.f, 0.f, 0.f, 0.f};

  const float* embB = emb + ((size_t)b * NS + m0) * ND;

  for (int k0 = 0; k0 < ND; k0 += 32) {
    __syncthreads();
#pragma unroll
    for (int w = 0; w < 4; ++w) {
      int r = ar + 32 * w;
      float4 v = *(const float4*)(embB + (size_t)r * ND + k0 + ac);
      float in = invn[w];
      ushort4 u;
      u.x = f2bf(v.x * in); u.y = f2bf(v.y * in);
      u.z = f2bf(v.z * in); u.w = f2bf(v.w * in);
      *(ushort4*)&Atile[r][ac] = u;
    }
    __syncthreads();

    bf16x8 af[4], bfr[4];
#pragma unroll
    for (int r = 0; r < 4; ++r) {
      int m = wm * 64 + r * 16 + l16;
      af[r] = *(const bf16x8*)&Atile[m][q * 8];
    }
#pragma unroll
    for (int r = 0; r < 4; ++r) {
      int ng = n0 + wn * 64 + r * 16 + l16;
      int e0 = k0 + 8 * q - ng + 1024;
      int p = e0 & 7;
      bfr[r] = *(const bf16x8*)&copies[p][e0 - p];
    }
#pragma unroll
    for (int i = 0; i < 4; ++i)
#pragma unroll
      for (int j = 0; j < 4; ++j)
        acc[i][j] = __builtin_amdgcn_mfma_f32_16x16x32_bf16(af[i], bfr[j], acc[i][j], 0, 0, 0);
  }

  float* outB = out + ((size_t)b * NS + m0) * ND + n0;
#pragma unroll
  for (int i = 0; i < 4; ++i) {
#pragma unroll
    for (int rg = 0; rg < 4; ++rg) {
      int s = wm * 64 + i * 16 + q * 4 + rg;
      float* orow = outB + (size_t)s * ND + wn * 64 + l16;
#pragma unroll
      for (int j = 0; j < 4; ++j)
        orow[j * 16] = acc[i][j][rg];
    }
  }
}

extern "C" void kernel_launch(void* const* d_in, const int* in_sizes, int n_in,
                              void* d_out, int out_size, void* d_ws, size_t ws_size,
                              hipStream_t stream) {
  const float* emb = (const float*)d_in[0];
  const float* aspect = (const float*)d_in[1];
  float* out = (float*)d_out;

  const size_t need = 65536 + (size_t)NB * NS * ND * 2;  // a_n + eN(bf16)

  if (ws_size >= need) {
    unsigned short* a_n = (unsigned short*)d_ws;
    unsigned short* eN = (unsigned short*)((char*)d_ws + 65536);
    anorm_kernel<<<NB, 256, 0, stream>>>(aspect, a_n);
    enormbf_kernel<<<4096, 256, 0, stream>>>(emb, eN);
    // grid (b, mt, nt): nt-siblings differ by 128 in flat id -> same XCD -> A-panel L2 reuse
    corr_gemm4_kernel<<<dim3(NB, 4, 8), 256, 0, stream>>>(eN, a_n, out);
  } else {
    float* inv_norm = (float*)d_ws;
    unsigned short* a_n = (unsigned short*)((char*)d_ws + 65536);
    enorm_kernel<<<4096, 256, 0, stream>>>(emb, inv_norm);
    anorm_kernel<<<NB, 256, 0, stream>>>(aspect, a_n);
    corr_gemm_kernel<<<dim3(8, 4, NB), 256, 0, stream>>>(emb, inv_norm, a_n, out);
  }
}